// Round 1
// baseline (8299.457 us; speedup 1.0000x reference)
//
#include <hip/hip_runtime.h>

#define TT 128
#define BB 32
#define II 128
#define HH 320
#define OO 32
#define GG 8

static __device__ __forceinline__ float fexp2(float x) { return __builtin_amdgcn_exp2f(x); }
static __device__ __forceinline__ float frcp(float x)  { return __builtin_amdgcn_rcpf(x); }

// tanh for x >= 0: 1 - 2/(e^{2x}+1), e^{2x} = exp2(x * 2*log2(e))
static __device__ __forceinline__ float tanh_pos(float x) {
    float e = fexp2(x * 2.8853900817779268f);
    return 1.0f - 2.0f * frcp(e + 1.0f);
}

__global__ __launch_bounds__(512, 2)
void leaky_rnn_kernel(const float* __restrict__ x, const float* __restrict__ Rs,
                      const float* __restrict__ Wx2h, const float* __restrict__ Wh2h,
                      const float* __restrict__ bh2h, const float* __restrict__ Wh2o,
                      const float* __restrict__ bh2o, const float* __restrict__ Wattn,
                      const float* __restrict__ battn, const float* __restrict__ cplas,
                      float* __restrict__ out, float* __restrict__ hs,
                      unsigned* __restrict__ ctr)
{
    const int tid  = threadIdx.x;
    const int bid  = blockIdx.x;
    const int b    = bid >> 3;     // batch
    const int sub  = bid & 7;      // 8 blocks per batch, 40 rows each
    const int w    = tid >> 6;     // wave 0..7
    const int lane = tid & 63;
    const int h0   = sub * 40;

    __shared__ float s_ea[GG * HH];   // masked relu(W_attn)
    __shared__ float s_out[HH];       // previous output for this b
    __shared__ float s_xm[II];        // modulated input
    __shared__ float s_logit[GG];
    __shared__ float s_hs[16 * HH];   // final-phase staging

    // ---- one-time init ----
    for (int idx = tid; idx < GG * HH; idx += 512) {
        int h = idx % HH;
        float m = (h < 256) ? 1.f : (h == 256 ? -1.f : 0.f);  // mask_a (zc=63!)
        s_ea[idx] = fmaxf(Wattn[idx], 0.f) * m;
    }
    if (tid < HH) s_out[tid] = 0.f;   // output0 = relu(0)

    // plastic weights in registers: 5 rows/wave, lane owns cols {lane, lane+64,...}
    float wx[5][2], wh[5][5], st[5], bh[5];
    int hrow[5];
#pragma unroll
    for (int r = 0; r < 5; ++r) {
        int h = h0 + w * 5 + r;
        hrow[r] = h;
        bh[r] = bh2h[h];
        st[r] = 0.f;
#pragma unroll
        for (int c = 0; c < 2; ++c)
            wx[r][c] = fmaxf(Wx2h[h * II + lane + 64 * c], 0.f);   // wx0 = relu(W_x2h)
#pragma unroll
        for (int c = 0; c < 5; ++c) {
            int j = lane + 64 * c;
            float v = fmaxf(Wh2h[h * HH + j], 0.f);
            v = (c == 4) ? -v : v;            // sign_h: j>=256 -> -1
            wh[r][c] = (j == h) ? 0.f : v;    // zero diagonal (1-eye)
        }
    }
    float batt = battn[w];  // wave w handles attn group g = w
    float c0 = fabsf(cplas[0]), c1 = fabsf(cplas[1]), c2 = fabsf(cplas[2]);
    float c3 = fabsf(cplas[3]), c4 = fabsf(cplas[4]), c5 = fabsf(cplas[5]);

    const float AX  = (float)(0.02 / 0.1);   // 0.2
    const float AW  = (float)(0.02 / 0.2);   // 0.1
    const float OMX = 1.f - AX;
    const float OMW = 1.f - AW;
    const float L2E = 1.4426950408889634f;

    __syncthreads();

#pragma unroll 1
    for (int t = 0; t < TT; ++t) {
        float xv = (tid < II) ? x[(t * BB + b) * II + tid] : 0.f;
        float Rv = Rs[t * BB + b];
        float A  = AW * Rv;

        // ---- attention logits: g = w, reduce over H ----
        float lp = 0.f;
#pragma unroll
        for (int k = 0; k < 5; ++k) {
            int hh2 = lane + 64 * k;
            lp = fmaf(s_ea[w * HH + hh2], s_out[hh2], lp);
        }
#pragma unroll
        for (int m = 1; m < 64; m <<= 1) lp += __shfl_xor(lp, m, 64);
        if (lane == 0) s_logit[w] = lp + batt;
        __syncthreads();

        // ---- softmax + xm (waves 0-1 only) ----
        if (tid < II) {
            float lg[8];
#pragma unroll
            for (int g = 0; g < 8; ++g) lg[g] = s_logit[g];
            float mx = lg[0];
#pragma unroll
            for (int g = 1; g < 8; ++g) mx = fmaxf(mx, lg[g]);
            float se = 0.f, eg[8];
#pragma unroll
            for (int g = 0; g < 8; ++g) { eg[g] = fexp2((lg[g] - mx) * L2E); se += eg[g]; }
            s_xm[tid] = xv * eg[tid >> 4] * 8.f * frcp(se);  // * G / sum
        }
        __syncthreads();

        // ---- per-lane column values (reused for dot and update) ----
        float xmc0 = s_xm[lane], xmc1 = s_xm[lane + 64];
        float oc[5];
#pragma unroll
        for (int c = 0; c < 5; ++c) oc[c] = s_out[lane + 64 * c];

        // ---- row dots -> state -> new_output ----
        float no[5];
#pragma unroll
        for (int r = 0; r < 5; ++r) {
            int h = hrow[r];
            float p = fmaxf(wx[r][0], 0.f) * xmc0;
            p = fmaf(fmaxf(wx[r][1], 0.f), xmc1, p);
#pragma unroll
            for (int c = 0; c < 5; ++c) {
                float wv = fmaxf(wh[r][c], 0.f);
                float so = (c == 4) ? -oc[4] : oc[c];   // sign_h fold
                float term = wv * so;
                term = ((lane + 64 * c) == h) ? 0.f : term;  // exclude diagonal
                p += term;
            }
#pragma unroll
            for (int m = 1; m < 64; m <<= 1) p += __shfl_xor(p, m, 64);
            float total = p + bh[r];
            st[r] = fmaf(st[r], OMX, total * AX);
            no[r] = tanh_pos(fmaxf(st[r], 0.f));
            if (lane == r)   // publish new_output (device-coherent store)
                __hip_atomic_store(&hs[(t * BB + b) * HH + h], no[r],
                                   __ATOMIC_RELAXED, __HIP_MEMORY_SCOPE_AGENT);
        }

        // ---- arrive (stores drained by syncthreads' vmcnt wait) ----
        __threadfence();
        __syncthreads();
        if (tid == 0)
            __hip_atomic_fetch_add(&ctr[b * 32], 1u, __ATOMIC_RELEASE, __HIP_MEMORY_SCOPE_AGENT);

        // ---- plastic weight update (local; overlaps peers' arrival) ----
        if (t < TT - 1) {
            float Ac0 = A * c0, Ac1 = A * c1, Ac2 = A * c2;
            float Ac3 = A * c3, Ac4 = A * c4, Ac5 = A * c5;
#pragma unroll
            for (int r = 0; r < 5; ++r) {
                float u  = fmaf(Ac2, no[r], Ac0);
                float v  = Ac1 * no[r];
                float pp = fmaf(Ac5, no[r], Ac3);
                float qq = Ac4 * no[r];
                wx[r][0] = fmaf(wx[r][0], OMW, fmaf(u, xmc0, v));
                wx[r][1] = fmaf(wx[r][1], OMW, fmaf(u, xmc1, v));
#pragma unroll
                for (int c = 0; c < 5; ++c)
                    wh[r][c] = fmaf(wh[r][c], OMW, fmaf(pp, oc[c], qq));
            }
        }

        // ---- wait for the 7 sibling blocks of this batch ----
        unsigned target = 8u * (unsigned)(t + 1);
        if (tid == 0) {
            int guard = 0;
            while (__hip_atomic_load(&ctr[b * 32], __ATOMIC_ACQUIRE, __HIP_MEMORY_SCOPE_AGENT) < target) {
                if (++guard > 100000) break;   // failsafe: terminate, never hang
                __builtin_amdgcn_s_sleep(1);
            }
        }
        __syncthreads();
        __threadfence();

        // ---- reload full output vector for next step ----
        if (t < TT - 1) {
            if (tid < HH)
                s_out[tid] = __hip_atomic_load(&hs[(t * BB + b) * HH + tid],
                                               __ATOMIC_RELAXED, __HIP_MEMORY_SCOPE_AGENT);
        }
        __syncthreads();
    }

    // ---- readout: out[t,b,o] = sigmoid(relu(W_h2o)*mask_o . hs + b_h2o) ----
    for (int idx = tid; idx < 16 * HH; idx += 512) {
        int tl = idx / HH, h = idx % HH;
        int t_g = sub * 16 + tl;
        s_hs[idx] = __hip_atomic_load(&hs[(t_g * BB + b) * HH + h],
                                      __ATOMIC_RELAXED, __HIP_MEMORY_SCOPE_AGENT);
    }
    __syncthreads();
    {
        int t_loc = tid >> 5;          // 0..15
        int o     = tid & 31;
        int t_g   = sub * 16 + t_loc;
        const float* hp = &s_hs[t_loc * HH];
        float acc = bh2o[o];
#pragma unroll 4
        for (int h = 0; h < 257; ++h) {          // mask_o zero for h>256
            float m = (h == 256) ? -1.f : 1.f;   // h==256: sign -1, exist 1 (zc=63)
            acc = fmaf(fmaxf(Wh2o[o * HH + h], 0.f) * m, hp[h], acc);
        }
        float sg = frcp(1.f + fexp2(-acc * L2E));
        out[(t_g * BB + b) * OO + o] = sg;
    }
}

extern "C" void kernel_launch(void* const* d_in, const int* in_sizes, int n_in,
                              void* d_out, int out_size, void* d_ws, size_t ws_size,
                              hipStream_t stream) {
    const float* x     = (const float*)d_in[0];
    const float* Rs    = (const float*)d_in[1];
    const float* Wx2h  = (const float*)d_in[2];
    const float* Wh2h  = (const float*)d_in[3];
    const float* bh2h  = (const float*)d_in[4];
    const float* Wh2o  = (const float*)d_in[5];
    const float* bh2o  = (const float*)d_in[6];
    const float* Wattn = (const float*)d_in[7];
    const float* battn = (const float*)d_in[8];
    const float* cplas = (const float*)d_in[9];
    float* out = (float*)d_out;
    float* hs  = out + TT * BB * OO;
    unsigned* ctr = (unsigned*)d_ws;   // 32 counters, 128B apart

    hipMemsetAsync(d_ws, 0, 32 * 32 * sizeof(unsigned), stream);
    hipLaunchKernelGGL(leaky_rnn_kernel, dim3(256), dim3(512), 0, stream,
                       x, Rs, Wx2h, Wh2h, bh2h, Wh2o, bh2o, Wattn, battn, cplas,
                       out, hs, ctr);
}

// Round 2
// 528.803 us; speedup vs baseline: 15.6948x; 15.6948x over previous
//
#include <hip/hip_runtime.h>

#define TT 128
#define BB 32
#define II 128
#define HH 320
#define OO 32
#define GG 8

static __device__ __forceinline__ float fexp2(float x) { return __builtin_amdgcn_exp2f(x); }
static __device__ __forceinline__ float frcp(float x)  { return __builtin_amdgcn_rcpf(x); }

// tanh for x >= 0: 1 - 2/(e^{2x}+1), e^{2x} = exp2(x * 2*log2(e))
static __device__ __forceinline__ float tanh_pos(float x) {
    float e = fexp2(x * 2.8853900817779268f);
    return 1.0f - 2.0f * frcp(e + 1.0f);
}

__global__ __launch_bounds__(512, 2)
void leaky_rnn_kernel(const float* __restrict__ x, const float* __restrict__ Rs,
                      const float* __restrict__ Wx2h, const float* __restrict__ Wh2h,
                      const float* __restrict__ bh2h, const float* __restrict__ Wh2o,
                      const float* __restrict__ bh2o, const float* __restrict__ Wattn,
                      const float* __restrict__ battn, const float* __restrict__ cplas,
                      float* __restrict__ out, float* __restrict__ hs,
                      unsigned* __restrict__ ctr)
{
    const int tid  = threadIdx.x;
    const int bid  = blockIdx.x;
    const int b    = bid >> 3;     // batch
    const int sub  = bid & 7;      // 8 blocks per batch, 40 rows each
    const int w    = tid >> 6;     // wave 0..7
    const int lane = tid & 63;
    const int h0   = sub * 40;

    __shared__ float s_ea[GG * HH];   // masked relu(W_attn)
    __shared__ float s_out[HH];       // previous output for this b
    __shared__ float s_xm[II];        // modulated input
    __shared__ float s_logit[GG];
    __shared__ float s_hs[16 * HH];   // final-phase staging

    // ---- one-time init ----
    for (int idx = tid; idx < GG * HH; idx += 512) {
        int h = idx % HH;
        float m = (h < 256) ? 1.f : (h == 256 ? -1.f : 0.f);  // mask_a (zc=63!)
        s_ea[idx] = fmaxf(Wattn[idx], 0.f) * m;
    }
    if (tid < HH) s_out[tid] = 0.f;   // output0 = relu(0)

    // plastic weights in registers: 5 rows/wave, lane owns cols {lane, lane+64,...}
    float wx[5][2], wh[5][5], st[5], bh[5];
    int hrow[5];
#pragma unroll
    for (int r = 0; r < 5; ++r) {
        int h = h0 + w * 5 + r;
        hrow[r] = h;
        bh[r] = bh2h[h];
        st[r] = 0.f;
#pragma unroll
        for (int c = 0; c < 2; ++c)
            wx[r][c] = fmaxf(Wx2h[h * II + lane + 64 * c], 0.f);   // wx0 = relu(W_x2h)
#pragma unroll
        for (int c = 0; c < 5; ++c) {
            int j = lane + 64 * c;
            float v = fmaxf(Wh2h[h * HH + j], 0.f);
            v = (c == 4) ? -v : v;            // sign_h: j>=256 -> -1
            wh[r][c] = (j == h) ? 0.f : v;    // zero diagonal (1-eye)
        }
    }
    float batt = battn[w];  // wave w handles attn group g = w
    float c0 = fabsf(cplas[0]), c1 = fabsf(cplas[1]), c2 = fabsf(cplas[2]);
    float c3 = fabsf(cplas[3]), c4 = fabsf(cplas[4]), c5 = fabsf(cplas[5]);

    const float AX  = (float)(0.02 / 0.1);   // 0.2
    const float AW  = (float)(0.02 / 0.2);   // 0.1
    const float OMX = 1.f - AX;
    const float OMW = 1.f - AW;
    const float L2E = 1.4426950408889634f;

    __syncthreads();

#pragma unroll 1
    for (int t = 0; t < TT; ++t) {
        float xv = (tid < II) ? x[(t * BB + b) * II + tid] : 0.f;
        float Rv = Rs[t * BB + b];
        float A  = AW * Rv;

        // ---- attention logits: g = w, reduce over H ----
        float lp = 0.f;
#pragma unroll
        for (int k = 0; k < 5; ++k) {
            int hh2 = lane + 64 * k;
            lp = fmaf(s_ea[w * HH + hh2], s_out[hh2], lp);
        }
#pragma unroll
        for (int m = 1; m < 64; m <<= 1) lp += __shfl_xor(lp, m, 64);
        if (lane == 0) s_logit[w] = lp + batt;
        __syncthreads();

        // ---- softmax + xm (waves 0-1 only) ----
        if (tid < II) {
            float lg[8];
#pragma unroll
            for (int g = 0; g < 8; ++g) lg[g] = s_logit[g];
            float mx = lg[0];
#pragma unroll
            for (int g = 1; g < 8; ++g) mx = fmaxf(mx, lg[g]);
            float se = 0.f, eg[8];
#pragma unroll
            for (int g = 0; g < 8; ++g) { eg[g] = fexp2((lg[g] - mx) * L2E); se += eg[g]; }
            s_xm[tid] = xv * eg[tid >> 4] * 8.f * frcp(se);  // * G / sum
        }
        __syncthreads();

        // ---- per-lane column values (reused for dot and update) ----
        float xmc0 = s_xm[lane], xmc1 = s_xm[lane + 64];
        float oc[5];
#pragma unroll
        for (int c = 0; c < 5; ++c) oc[c] = s_out[lane + 64 * c];

        // ---- row dots -> state -> new_output ----
        float no[5];
#pragma unroll
        for (int r = 0; r < 5; ++r) {
            int h = hrow[r];
            float p = fmaxf(wx[r][0], 0.f) * xmc0;
            p = fmaf(fmaxf(wx[r][1], 0.f), xmc1, p);
#pragma unroll
            for (int c = 0; c < 5; ++c) {
                float wv = fmaxf(wh[r][c], 0.f);
                float so = (c == 4) ? -oc[4] : oc[c];   // sign_h fold
                float term = wv * so;
                term = ((lane + 64 * c) == h) ? 0.f : term;  // exclude diagonal
                p += term;
            }
#pragma unroll
            for (int m = 1; m < 64; m <<= 1) p += __shfl_xor(p, m, 64);
            float total = p + bh[r];
            st[r] = fmaf(st[r], OMX, total * AX);
            no[r] = tanh_pos(fmaxf(st[r], 0.f));
            if (lane == r)   // publish new_output (agent-coherent sc1 store)
                __hip_atomic_store(&hs[(t * BB + b) * HH + h], no[r],
                                   __ATOMIC_RELAXED, __HIP_MEMORY_SCOPE_AGENT);
        }

        // ---- arrive: syncthreads drains vmcnt(0) (publish stores complete at
        //      coherence point) and is a compiler barrier; counter add can be
        //      RELAXED -- no buffer_wbl2/buffer_inv cache nukes. ----
        __syncthreads();
        if (tid == 0)
            __hip_atomic_fetch_add(&ctr[b * 32], 1u, __ATOMIC_RELAXED, __HIP_MEMORY_SCOPE_AGENT);

        // ---- plastic weight update (local; overlaps peers' arrival) ----
        if (t < TT - 1) {
            float Ac0 = A * c0, Ac1 = A * c1, Ac2 = A * c2;
            float Ac3 = A * c3, Ac4 = A * c4, Ac5 = A * c5;
#pragma unroll
            for (int r = 0; r < 5; ++r) {
                float u  = fmaf(Ac2, no[r], Ac0);
                float v  = Ac1 * no[r];
                float pp = fmaf(Ac5, no[r], Ac3);
                float qq = Ac4 * no[r];
                wx[r][0] = fmaf(wx[r][0], OMW, fmaf(u, xmc0, v));
                wx[r][1] = fmaf(wx[r][1], OMW, fmaf(u, xmc1, v));
#pragma unroll
                for (int c = 0; c < 5; ++c)
                    wh[r][c] = fmaf(wh[r][c], OMW, fmaf(pp, oc[c], qq));
            }
        }

        // ---- wait for the 7 sibling blocks of this batch (RELAXED poll:
        //      an ACQUIRE load would emit buffer_inv sc1 per iteration,
        //      invalidating the XCD's L2 continuously -- the round-1 stall) ----
        unsigned target = 8u * (unsigned)(t + 1);
        if (tid == 0) {
            int guard = 0;
            while (__hip_atomic_load(&ctr[b * 32], __ATOMIC_RELAXED, __HIP_MEMORY_SCOPE_AGENT) < target) {
                if (++guard > 1000000) break;   // failsafe: terminate, never hang
                __builtin_amdgcn_s_sleep(1);
            }
        }
        __syncthreads();

        // ---- reload full output vector for next step (sc1 loads bypass the
        //      stale L1/L2, so no acquire fence needed) ----
        if (t < TT - 1) {
            if (tid < HH)
                s_out[tid] = __hip_atomic_load(&hs[(t * BB + b) * HH + tid],
                                               __ATOMIC_RELAXED, __HIP_MEMORY_SCOPE_AGENT);
        }
        __syncthreads();
    }

    // ---- readout: out[t,b,o] = sigmoid(relu(W_h2o)*mask_o . hs + b_h2o) ----
    for (int idx = tid; idx < 16 * HH; idx += 512) {
        int tl = idx / HH, h = idx % HH;
        int t_g = sub * 16 + tl;
        s_hs[idx] = __hip_atomic_load(&hs[(t_g * BB + b) * HH + h],
                                      __ATOMIC_RELAXED, __HIP_MEMORY_SCOPE_AGENT);
    }
    __syncthreads();
    {
        int t_loc = tid >> 5;          // 0..15
        int o     = tid & 31;
        int t_g   = sub * 16 + t_loc;
        const float* hp = &s_hs[t_loc * HH];
        float acc = bh2o[o];
#pragma unroll 4
        for (int h = 0; h < 257; ++h) {          // mask_o zero for h>256
            float m = (h == 256) ? -1.f : 1.f;   // h==256: sign -1, exist 1 (zc=63)
            acc = fmaf(fmaxf(Wh2o[o * HH + h], 0.f) * m, hp[h], acc);
        }
        float sg = frcp(1.f + fexp2(-acc * L2E));
        out[(t_g * BB + b) * OO + o] = sg;
    }
}

extern "C" void kernel_launch(void* const* d_in, const int* in_sizes, int n_in,
                              void* d_out, int out_size, void* d_ws, size_t ws_size,
                              hipStream_t stream) {
    const float* x     = (const float*)d_in[0];
    const float* Rs    = (const float*)d_in[1];
    const float* Wx2h  = (const float*)d_in[2];
    const float* Wh2h  = (const float*)d_in[3];
    const float* bh2h  = (const float*)d_in[4];
    const float* Wh2o  = (const float*)d_in[5];
    const float* bh2o  = (const float*)d_in[6];
    const float* Wattn = (const float*)d_in[7];
    const float* battn = (const float*)d_in[8];
    const float* cplas = (const float*)d_in[9];
    float* out = (float*)d_out;
    float* hs  = out + TT * BB * OO;
    unsigned* ctr = (unsigned*)d_ws;   // 32 counters, 128B apart

    hipMemsetAsync(d_ws, 0, 32 * 32 * sizeof(unsigned), stream);
    hipLaunchKernelGGL(leaky_rnn_kernel, dim3(256), dim3(512), 0, stream,
                       x, Rs, Wx2h, Wh2h, bh2h, Wh2o, bh2o, Wattn, battn, cplas,
                       out, hs, ctr);
}

// Round 3
// 522.741 us; speedup vs baseline: 15.8768x; 1.0116x over previous
//
#include <hip/hip_runtime.h>

#define TT 128
#define BB 32
#define II 128
#define HH 320
#define OO 32
#define GG 8
#define HPAD 129   // s_hist row pitch (pad: rows are read down-column in poll phase)

static __device__ __forceinline__ float fexp2(float x) { return __builtin_amdgcn_exp2f(x); }
static __device__ __forceinline__ float frcp(float x)  { return __builtin_amdgcn_rcpf(x); }

// tanh for x >= 0: 1 - 2/(e^{2x}+1), e^{2x} = exp2(x * 2*log2(e))
static __device__ __forceinline__ float tanh_pos(float x) {
    float e = fexp2(x * 2.8853900817779268f);
    return 1.0f - 2.0f * frcp(e + 1.0f);
}

__global__ __launch_bounds__(512, 2)
void leaky_rnn_kernel(const float* __restrict__ x, const float* __restrict__ Rs,
                      const float* __restrict__ Wx2h, const float* __restrict__ Wh2h,
                      const float* __restrict__ bh2h, const float* __restrict__ Wh2o,
                      const float* __restrict__ bh2o, const float* __restrict__ Wattn,
                      const float* __restrict__ battn, const float* __restrict__ cplas,
                      float* __restrict__ out, float* __restrict__ hs,
                      unsigned* __restrict__ ctr)
{
    const int tid  = threadIdx.x;
    const int bid  = blockIdx.x;
    const int b    = bid >> 3;     // batch
    const int sub  = bid & 7;      // 8 blocks per batch, 40 rows each
    const int w    = tid >> 6;     // wave 0..7
    const int lane = tid & 63;
    const int h0   = sub * 40;

    __shared__ float s_ea[GG * HH];      // masked relu(W_attn)
    __shared__ float s_out[HH];          // previous output for this b
    __shared__ float s_xm[II];           // modulated input
    __shared__ float s_logit[GG];
    __shared__ float s_hist[40 * HPAD];  // this block's 40 rows x 128 t (true values)
    __shared__ float s_hs[16 * HH];      // readout staging

    // ---- one-time init ----
    for (int idx = tid; idx < GG * HH; idx += 512) {
        int h = idx % HH;
        float m = (h < 256) ? 1.f : (h == 256 ? -1.f : 0.f);  // mask_a (zc=63!)
        s_ea[idx] = fmaxf(Wattn[idx], 0.f) * m;
    }
    if (tid < HH) s_out[tid] = 0.f;   // output0 = relu(0)

    // plastic weights in registers: 5 rows/wave, lane owns cols {lane, lane+64,...}
    float wx[5][2], wh[5][5], st[5], bh[5];
    int hrow[5];
#pragma unroll
    for (int r = 0; r < 5; ++r) {
        int h = h0 + w * 5 + r;
        hrow[r] = h;
        bh[r] = bh2h[h];
        st[r] = 0.f;
#pragma unroll
        for (int c = 0; c < 2; ++c)
            wx[r][c] = fmaxf(Wx2h[h * II + lane + 64 * c], 0.f);   // wx0 = relu(W_x2h)
#pragma unroll
        for (int c = 0; c < 5; ++c) {
            int j = lane + 64 * c;
            float v = fmaxf(Wh2h[h * HH + j], 0.f);
            v = (c == 4) ? -v : v;            // sign_h: j>=256 -> -1
            wh[r][c] = (j == h) ? 0.f : v;    // zero diagonal (1-eye)
        }
    }
    float batt = battn[w];  // wave w handles attn group g = w
    float c0 = fabsf(cplas[0]), c1 = fabsf(cplas[1]), c2 = fabsf(cplas[2]);
    float c3 = fabsf(cplas[3]), c4 = fabsf(cplas[4]), c5 = fabsf(cplas[5]);

    const float AX  = (float)(0.02 / 0.1);   // 0.2
    const float AW  = (float)(0.02 / 0.2);   // 0.1
    const float OMX = 1.f - AX;
    const float OMW = 1.f - AW;
    const float L2E = 1.4426950408889634f;

    __syncthreads();

    // prefetch x for t=0
    float xv_next = (tid < II) ? x[b * II + tid] : 0.f;

#pragma unroll 1
    for (int t = 0; t < TT; ++t) {
        float xv = xv_next;
        float Rv = Rs[t * BB + b];
        float A  = AW * Rv;

        // ---- attention logits: g = w, reduce over H ----
        float lp = 0.f;
#pragma unroll
        for (int k = 0; k < 5; ++k) {
            int hh2 = lane + 64 * k;
            lp = fmaf(s_ea[w * HH + hh2], s_out[hh2], lp);
        }
#pragma unroll
        for (int m = 1; m < 64; m <<= 1) lp += __shfl_xor(lp, m, 64);
        if (lane == 0) s_logit[w] = lp + batt;
        __syncthreads();

        // ---- softmax + xm (threads 0..127 only) ----
        if (tid < II) {
            float lg[8];
#pragma unroll
            for (int g = 0; g < 8; ++g) lg[g] = s_logit[g];
            float mx = lg[0];
#pragma unroll
            for (int g = 1; g < 8; ++g) mx = fmaxf(mx, lg[g]);
            float se = 0.f, eg[8];
#pragma unroll
            for (int g = 0; g < 8; ++g) { eg[g] = fexp2((lg[g] - mx) * L2E); se += eg[g]; }
            s_xm[tid] = xv * eg[tid >> 4] * 8.f * frcp(se);  // * G / sum
        }
        __syncthreads();

        // ---- per-lane column values (reused for dot and update) ----
        float xmc0 = s_xm[lane], xmc1 = s_xm[lane + 64];
        float oc[5];
#pragma unroll
        for (int c = 0; c < 5; ++c) oc[c] = s_out[lane + 64 * c];

        // ---- row dots -> state -> new_output; publish BIASED (+2) early ----
        float no[5];
#pragma unroll
        for (int r = 0; r < 5; ++r) {
            int h = hrow[r];
            float p = fmaxf(wx[r][0], 0.f) * xmc0;
            p = fmaf(fmaxf(wx[r][1], 0.f), xmc1, p);
#pragma unroll
            for (int c = 0; c < 5; ++c) {
                float wv = fmaxf(wh[r][c], 0.f);
                float so = (c == 4) ? -oc[4] : oc[c];   // sign_h fold
                float term = wv * so;
                term = ((lane + 64 * c) == h) ? 0.f : term;  // exclude diagonal
                p += term;
            }
#pragma unroll
            for (int m = 1; m < 64; m <<= 1) p += __shfl_xor(p, m, 64);
            float total = p + bh[r];
            st[r] = fmaf(st[r], OMX, total * AX);
            no[r] = tanh_pos(fmaxf(st[r], 0.f));
            if (lane == r) {
                // biased publish: value in [2,3) -- poison 0xAA.. and memset-0 are <1
                __hip_atomic_store(&hs[(t * BB + b) * HH + h], no[r] + 2.0f,
                                   __ATOMIC_RELAXED, __HIP_MEMORY_SCOPE_AGENT);
                s_hist[(w * 5 + r) * HPAD + t] = no[r];   // true value for final rewrite
            }
        }

        // ---- plastic weight update (regs only; overlaps store propagation) ----
        if (t < TT - 1) {
            float Ac0 = A * c0, Ac1 = A * c1, Ac2 = A * c2;
            float Ac3 = A * c3, Ac4 = A * c4, Ac5 = A * c5;
#pragma unroll
            for (int r = 0; r < 5; ++r) {
                float u  = fmaf(Ac2, no[r], Ac0);
                float v  = Ac1 * no[r];
                float pp = fmaf(Ac5, no[r], Ac3);
                float qq = Ac4 * no[r];
                wx[r][0] = fmaf(wx[r][0], OMW, fmaf(u, xmc0, v));
                wx[r][1] = fmaf(wx[r][1], OMW, fmaf(u, xmc1, v));
#pragma unroll
                for (int c = 0; c < 5; ++c)
                    wh[r][c] = fmaf(wh[r][c], OMW, fmaf(pp, oc[c], qq));
            }
        }

        // prefetch next x while peers' stores are in flight
        if (t + 1 < TT)
            xv_next = (tid < II) ? x[((t + 1) * BB + b) * II + tid] : 0.f;

        __syncthreads();   // all reads of s_out / s_hist-write visibility before overwrite

        // ---- gather next-step output vector by POLLING THE DATA (no counter,
        //      no ack RTT, no separate reload RTT) ----
        if (t < TT - 1 && tid < HH) {
            float v;
            if (tid >= h0 && tid < h0 + 40) {
                v = s_hist[(tid - h0) * HPAD + t];   // own rows: LDS, already true value
            } else {
                int guard = 0;
                do {
                    v = __hip_atomic_load(&hs[(t * BB + b) * HH + tid],
                                          __ATOMIC_RELAXED, __HIP_MEMORY_SCOPE_AGENT);
                    if (++guard > 2000000) break;   // failsafe: never hang
                } while (v < 1.0f);
                v -= 2.0f;
            }
            s_out[tid] = v;
        }
        __syncthreads();
    }

    // ======== final phase ========
    // Barrier A among the 8 sibling blocks: everyone's t-loop done, all hs published.
    if (tid == 0) {
        __hip_atomic_fetch_add(&ctr[b * 32], 1u, __ATOMIC_RELAXED, __HIP_MEMORY_SCOPE_AGENT);
        int guard = 0;
        while (__hip_atomic_load(&ctr[b * 32], __ATOMIC_RELAXED, __HIP_MEMORY_SCOPE_AGENT) < 8u) {
            if (++guard > 2000000) break;
            __builtin_amdgcn_s_sleep(1);
        }
    }
    __syncthreads();

    // readout staging: load biased hs, subtract bias
    for (int idx = tid; idx < 16 * HH; idx += 512) {
        int tl = idx / HH, h = idx % HH;
        int t_g = sub * 16 + tl;
        s_hs[idx] = __hip_atomic_load(&hs[(t_g * BB + b) * HH + h],
                                      __ATOMIC_RELAXED, __HIP_MEMORY_SCOPE_AGENT) - 2.0f;
    }
    __syncthreads();
    {
        int t_loc = tid >> 5;          // 0..15
        int o     = tid & 31;
        int t_g   = sub * 16 + t_loc;
        const float* hp = &s_hs[t_loc * HH];
        float acc = bh2o[o];
#pragma unroll 4
        for (int h = 0; h < 257; ++h) {          // mask_o zero for h>256
            float m = (h == 256) ? -1.f : 1.f;   // h==256: sign -1, exist 1 (zc=63)
            acc = fmaf(fmaxf(Wh2o[o * HH + h], 0.f) * m, hp[h], acc);
        }
        float sg = frcp(1.f + fexp2(-acc * L2E));
        out[(t_g * BB + b) * OO + o] = sg;
    }

    // Barrier B: all siblings finished READING biased hs -> safe to rewrite
    __syncthreads();
    if (tid == 0) {
        __hip_atomic_fetch_add(&ctr[b * 32], 1u, __ATOMIC_RELAXED, __HIP_MEMORY_SCOPE_AGENT);
        int guard = 0;
        while (__hip_atomic_load(&ctr[b * 32], __ATOMIC_RELAXED, __HIP_MEMORY_SCOPE_AGENT) < 16u) {
            if (++guard > 2000000) break;
            __builtin_amdgcn_s_sleep(1);
        }
    }
    __syncthreads();

    // rewrite own rows of hs with TRUE values (sc1 stores: no cross-XCD
    // partial-dirty-line merge concerns)
    for (int idx = tid; idx < 40 * TT; idx += 512) {
        int row = idx >> 7;            // idx / 128
        int t   = idx & 127;
        __hip_atomic_store(&hs[(t * BB + b) * HH + h0 + row], s_hist[row * HPAD + t],
                           __ATOMIC_RELAXED, __HIP_MEMORY_SCOPE_AGENT);
    }
}

extern "C" void kernel_launch(void* const* d_in, const int* in_sizes, int n_in,
                              void* d_out, int out_size, void* d_ws, size_t ws_size,
                              hipStream_t stream) {
    const float* x     = (const float*)d_in[0];
    const float* Rs    = (const float*)d_in[1];
    const float* Wx2h  = (const float*)d_in[2];
    const float* Wh2h  = (const float*)d_in[3];
    const float* bh2h  = (const float*)d_in[4];
    const float* Wh2o  = (const float*)d_in[5];
    const float* bh2o  = (const float*)d_in[6];
    const float* Wattn = (const float*)d_in[7];
    const float* battn = (const float*)d_in[8];
    const float* cplas = (const float*)d_in[9];
    float* out = (float*)d_out;
    float* hs  = out + TT * BB * OO;
    unsigned* ctr = (unsigned*)d_ws;   // 32 counters, 128B apart

    hipMemsetAsync(d_ws, 0, 32 * 32 * sizeof(unsigned), stream);
    hipLaunchKernelGGL(leaky_rnn_kernel, dim3(256), dim3(512), 0, stream,
                       x, Rs, Wx2h, Wh2h, bh2h, Wh2o, bh2o, Wattn, battn, cplas,
                       out, hs, ctr);
}